// Round 1
// baseline (546.592 us; speedup 1.0000x reference)
//
#include <hip/hip_runtime.h>
#include <hip/hip_bf16.h>

// Problem constants
#define BATCH 4
#define S_TOT 4096
#define ROWS (BATCH * S_TOT)   // 16384
#define DM 2048
#define DSP 128
#define NSEG 512               // neurons per segment; 3 segments

// ---------------- K0: row-normalize neuron embeddings (1536 x 128) -------------
__global__ __launch_bounds__(64) void k0_norm(const float* __restrict__ emb,
                                              float* __restrict__ embn) {
  const int row = blockIdx.x;          // 0..1535
  const int l = threadIdx.x;           // 0..63
  float2 v = *(const float2*)&emb[row * 128 + l * 2];
  float ss = v.x * v.x + v.y * v.y;
  #pragma unroll
  for (int m = 32; m; m >>= 1) ss += __shfl_xor(ss, m);
  const float inv = 1.0f / fmaxf(sqrtf(ss), 1e-12f);
  float2 o; o.x = v.x * inv; o.y = v.y * inv;
  *(float2*)&embn[row * 128 + l * 2] = o;
}

// ---------------- K1: h = x @ W^T + b  (16384x2048 @ 2048x128) -----------------
// Block: 256 threads, tile 64 rows x 128 cols, BK=16. Thread tile 8x4.
__global__ __launch_bounds__(256) void k1_gemm(const float* __restrict__ x,
                                               const float* __restrict__ W,
                                               const float* __restrict__ bias,
                                               float* __restrict__ h) {
  __shared__ __align__(16) float As[16][68];    // k-major: As[k][r], r<64 (pad 68)
  __shared__ __align__(16) float Bs[16][132];   // k-major: Bs[k][c], c<128 (pad 132)
  const int tid = threadIdx.x;
  const int m0 = blockIdx.x * 64;
  const int tr = tid >> 5;      // 0..7  -> rows tr*8 .. tr*8+7
  const int tc = tid & 31;      // 0..31 -> cols tc*4 .. tc*4+3

  float acc[8][4] = {};

  for (int kt = 0; kt < DM; kt += 16) {
    __syncthreads();
    // stage A: 64 rows x 16 k  (1024 floats, 4 per thread)
    for (int i = tid; i < 64 * 16; i += 256) {
      const int r = i >> 4, k = i & 15;
      As[k][r] = x[(size_t)(m0 + r) * DM + kt + k];
    }
    // stage B: 128 cols x 16 k (2048 floats, 8 per thread)
    for (int i = tid; i < 128 * 16; i += 256) {
      const int c = i >> 4, k = i & 15;
      Bs[k][c] = W[(size_t)c * DM + kt + k];
    }
    __syncthreads();
    #pragma unroll
    for (int k = 0; k < 16; ++k) {
      const float4 a0 = *(const float4*)&As[k][tr * 8];
      const float4 a1 = *(const float4*)&As[k][tr * 8 + 4];
      const float4 b0 = *(const float4*)&Bs[k][tc * 4];
      const float av[8] = {a0.x, a0.y, a0.z, a0.w, a1.x, a1.y, a1.z, a1.w};
      const float bv[4] = {b0.x, b0.y, b0.z, b0.w};
      #pragma unroll
      for (int i = 0; i < 8; ++i)
        #pragma unroll
        for (int j = 0; j < 4; ++j)
          acc[i][j] = fmaf(av[i], bv[j], acc[i][j]);
    }
  }
  #pragma unroll
  for (int i = 0; i < 8; ++i) {
    const int r = m0 + tr * 8 + i;
    float4 o;
    o.x = acc[i][0] + bias[tc * 4 + 0];
    o.y = acc[i][1] + bias[tc * 4 + 1];
    o.z = acc[i][2] + bias[tc * 4 + 2];
    o.w = acc[i][3] + bias[tc * 4 + 3];
    *(float4*)&h[(size_t)r * DSP + tc * 4] = o;
  }
}

// ---------------- K2: logits + softmax + importance-weighted accumulate --------
// Block: 256 threads (4 waves), tile 32 rows x 512 neurons (one segment), K=128.
// Wave w owns rows w*8..w*8+7 (wave-uniform -> broadcast LDS reads of h).
// Lane l owns neurons l*8..l*8+7. Thread tile 8x8; logits live in registers.
__global__ __launch_bounds__(256) void k2_logits(const float* __restrict__ h,
                                                 const float* __restrict__ embn,
                                                 const float* __restrict__ imp,
                                                 float* __restrict__ dense) {
  __shared__ __align__(16) float hs[128][36];   // k-major: hs[k][r], r<32 (pad 36)
  __shared__ __align__(16) float es[16][516];   // es[kk][n], n<512 (pad 516)
  __shared__ float ldsDense[512];
  const int tid = threadIdx.x;
  const int m0 = blockIdx.x * 32;
  const int seg = blockIdx.y;
  const int b = m0 >> 12;                 // row / 4096
  const int tr = tid >> 6;                // wave 0..3
  const int tc = tid & 63;                // lane 0..63

  ldsDense[tid] = 0.0f;
  ldsDense[tid + 256] = 0.0f;

  // stage h tile (32 x 128), k-major
  for (int i = tid; i < 32 * 128; i += 256) {
    const int r = i >> 7, k = i & 127;
    hs[k][r] = h[(size_t)(m0 + r) * DSP + k];
  }

  float acc[8][8] = {};
  const float* embSeg = embn + (size_t)seg * NSEG * DSP;

  for (int kt = 0; kt < 128; kt += 16) {
    __syncthreads();   // protects es reuse; first iter: hs/ldsDense ready
    // stage emb tile (512 neurons x 16 k), k-major
    for (int i = tid; i < NSEG * 16; i += 256) {
      const int n = i >> 4, kk = i & 15;
      es[kk][n] = embSeg[(size_t)n * DSP + kt + kk];
    }
    __syncthreads();
    #pragma unroll
    for (int kk = 0; kk < 16; ++kk) {
      const int k = kt + kk;
      const float4 ha = *(const float4*)&hs[k][tr * 8];       // broadcast
      const float4 hb = *(const float4*)&hs[k][tr * 8 + 4];   // broadcast
      const float4 ea = *(const float4*)&es[kk][tc * 8];
      const float4 eb = *(const float4*)&es[kk][tc * 8 + 4];
      const float hv[8] = {ha.x, ha.y, ha.z, ha.w, hb.x, hb.y, hb.z, hb.w};
      const float ev[8] = {ea.x, ea.y, ea.z, ea.w, eb.x, eb.y, eb.z, eb.w};
      #pragma unroll
      for (int i = 0; i < 8; ++i)
        #pragma unroll
        for (int j = 0; j < 8; ++j)
          acc[i][j] = fmaf(hv[i], ev[j], acc[i][j]);
    }
  }

  // softmax per row (rows are wave-uniform; reduce across full 64-lane wave)
  float w[8];
  #pragma unroll
  for (int i = 0; i < 8; ++i) {
    float mx = acc[i][0];
    #pragma unroll
    for (int j = 1; j < 8; ++j) mx = fmaxf(mx, acc[i][j]);
    #pragma unroll
    for (int m = 1; m < 64; m <<= 1) mx = fmaxf(mx, __shfl_xor(mx, m));
    float s = 0.0f;
    #pragma unroll
    for (int j = 0; j < 8; ++j) {
      acc[i][j] = __expf(acc[i][j] - mx);
      s += acc[i][j];
    }
    #pragma unroll
    for (int m = 1; m < 64; m <<= 1) s += __shfl_xor(s, m);
    w[i] = imp[m0 + tr * 8 + i] / s;
  }

  // per-neuron partial over this thread's 8 rows, then block-level LDS reduce
  #pragma unroll
  for (int j = 0; j < 8; ++j) {
    float p = 0.0f;
    #pragma unroll
    for (int i = 0; i < 8; ++i) p = fmaf(acc[i][j], w[i], p);
    atomicAdd(&ldsDense[tc * 8 + j], p);
  }
  __syncthreads();
  atomicAdd(&dense[b * 1536 + seg * NSEG + tid], ldsDense[tid]);
  atomicAdd(&dense[b * 1536 + seg * NSEG + tid + 256], ldsDense[tid + 256]);
}

// ---------------- K3: top-k sparsify + normalize + write outputs ---------------
// grid (4 batches, 3 segments), 256 threads. seg1 writes both qw and kw slots.
__global__ __launch_bounds__(256) void k3_topk(const float* __restrict__ dense,
                                               float* __restrict__ out) {
  const int b = blockIdx.x;     // 0..3
  const int seg = blockIdx.y;   // 0..2
  const int tid = threadIdx.x;
  const int K = (seg == 0) ? 8 : ((seg == 1) ? 4 : 6);

  __shared__ float v[512];
  __shared__ float wv[8];
  __shared__ int wi[8];
  __shared__ float redv[4];
  __shared__ int redi[4];

  const float* src = dense + b * 1536 + seg * NSEG;
  v[tid] = src[tid];
  v[tid + 256] = src[tid + 256];
  __syncthreads();

  for (int t = 0; t < K; ++t) {
    const float v0 = v[tid], v1 = v[tid + 256];
    float bv; int bi;
    if (v1 > v0) { bv = v1; bi = tid + 256; } else { bv = v0; bi = tid; }
    #pragma unroll
    for (int m = 1; m < 64; m <<= 1) {
      const float ov = __shfl_xor(bv, m);
      const int oi = __shfl_xor(bi, m);
      if (ov > bv || (ov == bv && oi < bi)) { bv = ov; bi = oi; }
    }
    if ((tid & 63) == 0) { redv[tid >> 6] = bv; redi[tid >> 6] = bi; }
    __syncthreads();
    if (tid == 0) {
      float best = redv[0]; int besti = redi[0];
      for (int q = 1; q < 4; ++q)
        if (redv[q] > best || (redv[q] == best && redi[q] < besti)) {
          best = redv[q]; besti = redi[q];
        }
      wv[t] = best; wi[t] = besti;
      v[besti] = -3.0e38f;
    }
    __syncthreads();
  }

  float s = 1e-8f;
  for (int t = 0; t < K; ++t) s += wv[t];

  const int slot0 = (seg == 0) ? 0 : ((seg == 1) ? 1 : 3);
  float* o0 = out + slot0 * (BATCH * NSEG) + b * NSEG;
  o0[tid] = 0.0f; o0[tid + 256] = 0.0f;
  float* o1 = nullptr;
  if (seg == 1) {
    o1 = out + 2 * (BATCH * NSEG) + b * NSEG;
    o1[tid] = 0.0f; o1[tid + 256] = 0.0f;
  }
  __syncthreads();  // order zero-phase before winner writes (same block)
  if (tid < K) {
    const float val = wv[tid] / s;
    o0[wi[tid]] = val;
    if (seg == 1) o1[wi[tid]] = val;
  }
}

// -------------------------------- launch ---------------------------------------
extern "C" void kernel_launch(void* const* d_in, const int* in_sizes, int n_in,
                              void* d_out, int out_size, void* d_ws, size_t ws_size,
                              hipStream_t stream) {
  (void)in_sizes; (void)n_in; (void)out_size; (void)ws_size;
  const float* x    = (const float*)d_in[0];   // (4,4096,2048)
  const float* imp  = (const float*)d_in[1];   // (4,4096)
  const float* W    = (const float*)d_in[2];   // (128,2048)
  const float* bias = (const float*)d_in[3];   // (128)
  const float* emb  = (const float*)d_in[4];   // (1536,128)
  float* out = (float*)d_out;                  // (4,4,512)

  // workspace carve (floats): embn | h | dense
  float* embn  = (float*)d_ws;                         // 1536*128   = 196608
  float* h     = embn + 196608;                        // 16384*128  = 2097152
  float* dense = h + 2097152;                          // 4*1536     = 6144

  hipMemsetAsync(dense, 0, 6144 * sizeof(float), stream);

  k0_norm<<<1536, 64, 0, stream>>>(emb, embn);
  k1_gemm<<<ROWS / 64, 256, 0, stream>>>(x, W, bias, h);
  k2_logits<<<dim3(ROWS / 32, 3), 256, 0, stream>>>(h, embn, imp, dense);
  k3_topk<<<dim3(BATCH, 3), 256, 0, stream>>>(dense, out);
}

// Round 2
// 194.795 us; speedup vs baseline: 2.8060x; 2.8060x over previous
//
#include <hip/hip_runtime.h>
#include <hip/hip_bf16.h>

// Problem constants
#define BATCH 4
#define S_TOT 4096
#define ROWS (BATCH * S_TOT)   // 16384
#define DM 2048
#define DSP 128
#define NSEG 512               // neurons per segment; 3 segments

typedef short short8 __attribute__((ext_vector_type(8)));
typedef float f32x16 __attribute__((ext_vector_type(16)));

// float -> bf16(RNE) bits; also returns the fp32 value of the bf16 for residual
static __device__ inline short f2bf(float v, float& back) {
  unsigned u = __float_as_uint(v);
  unsigned r = u + 0x7FFFu + ((u >> 16) & 1u);
  unsigned short hs = (unsigned short)(r >> 16);
  back = __uint_as_float(((unsigned)hs) << 16);
  return (short)hs;
}

// ---------------- K0: row-normalize neuron embeddings (1536 x 128) -------------
__global__ __launch_bounds__(64) void k0_norm(const float* __restrict__ emb,
                                              float* __restrict__ embn) {
  const int row = blockIdx.x;
  const int l = threadIdx.x;
  float2 v = *(const float2*)&emb[row * 128 + l * 2];
  float ss = v.x * v.x + v.y * v.y;
  #pragma unroll
  for (int m = 32; m; m >>= 1) ss += __shfl_xor(ss, m);
  const float inv = 1.0f / fmaxf(sqrtf(ss), 1e-12f);
  float2 o; o.x = v.x * inv; o.y = v.y * inv;
  *(float2*)&embn[row * 128 + l * 2] = o;
}

// ---------------- K1: h = x @ W^T + b via bf16x3-split MFMA --------------------
// grid (128 M-tiles, 2 K-halves), 512 threads (8 waves).
// Wave w: rows (w>>1)*32.., cols (w&1)*64.. ; 32x32x16 MFMA, 2 col-frags.
// LDS frag-linear: lds[buf][arr][kgroup][row][8bf16]; arr 0=Ah 1=Al 2=Bh 3=Bl.
__global__ __launch_bounds__(512, 2) void k1_mfma(const float* __restrict__ x,
                                                  const float* __restrict__ W,
                                                  const float* __restrict__ bias,
                                                  float* __restrict__ h0,
                                                  float* __restrict__ h1) {
  __shared__ __align__(16) short lds[2][4][4][128][8];   // 64 KB

  const int t = threadIdx.x;
  const int m0 = blockIdx.x * 128;
  const int y = blockIdx.y;              // K-half
  const int kb0 = y * 1024;

  // staging assignment: thread t -> row/neuron sr, kgroup skg (8 k each)
  const int sr = t >> 2;
  const int skg = t & 3;
  const float* xp = x + (size_t)(m0 + sr) * DM + kb0 + skg * 8;
  const float* wp = W + (size_t)sr * DM + kb0 + skg * 8;

  // wave decomposition
  const int wave = t >> 6;
  const int lane = t & 63;
  const int wr = wave >> 1;              // row group 0..3 -> rows wr*32
  const int wc = wave & 1;               // col group 0..1 -> cols wc*64
  const int fr = lane & 31;              // row/col within frag
  const int ks = lane >> 5;              // k-subgroup selector

  f32x16 acc0 = {}; f32x16 acc1 = {};

  #define STAGE(buf, step)                                                      \
    {                                                                           \
      const int off = (step) * 32;                                              \
      float4 a0 = *(const float4*)(xp + off);                                   \
      float4 a1 = *(const float4*)(xp + off + 4);                               \
      float4 b0 = *(const float4*)(wp + off);                                   \
      float4 b1 = *(const float4*)(wp + off + 4);                               \
      short8 ah, al, bh, bl; float bk;                                          \
      const float av[8] = {a0.x,a0.y,a0.z,a0.w,a1.x,a1.y,a1.z,a1.w};            \
      const float bv[8] = {b0.x,b0.y,b0.z,b0.w,b1.x,b1.y,b1.z,b1.w};            \
      _Pragma("unroll")                                                         \
      for (int e = 0; e < 8; ++e) {                                             \
        ah[e] = f2bf(av[e], bk); al[e] = f2bf(av[e] - bk, bk);                  \
      }                                                                         \
      _Pragma("unroll")                                                         \
      for (int e = 0; e < 8; ++e) {                                             \
        bh[e] = f2bf(bv[e], bk); bl[e] = f2bf(bv[e] - bk, bk);                  \
      }                                                                         \
      *(short8*)&lds[buf][0][skg][sr][0] = ah;                                  \
      *(short8*)&lds[buf][1][skg][sr][0] = al;                                  \
      *(short8*)&lds[buf][2][skg][sr][0] = bh;                                  \
      *(short8*)&lds[buf][3][skg][sr][0] = bl;                                  \
    }

  #define COMPUTE(buf)                                                          \
    {                                                                           \
      _Pragma("unroll")                                                         \
      for (int kh = 0; kh < 2; ++kh) {                                          \
        const int kg = kh * 2 + ks;                                             \
        short8 ahf = *(const short8*)&lds[buf][0][kg][wr * 32 + fr][0];         \
        short8 alf = *(const short8*)&lds[buf][1][kg][wr * 32 + fr][0];         \
        short8 bh0 = *(const short8*)&lds[buf][2][kg][wc * 64 + fr][0];         \
        short8 bl0 = *(const short8*)&lds[buf][3][kg][wc * 64 + fr][0];         \
        short8 bh1 = *(const short8*)&lds[buf][2][kg][wc * 64 + 32 + fr][0];    \
        short8 bl1 = *(const short8*)&lds[buf][3][kg][wc * 64 + 32 + fr][0];    \
        acc0 = __builtin_amdgcn_mfma_f32_32x32x16_bf16(ahf, bh0, acc0, 0, 0, 0);\
        acc0 = __builtin_amdgcn_mfma_f32_32x32x16_bf16(ahf, bl0, acc0, 0, 0, 0);\
        acc0 = __builtin_amdgcn_mfma_f32_32x32x16_bf16(alf, bh0, acc0, 0, 0, 0);\
        acc1 = __builtin_amdgcn_mfma_f32_32x32x16_bf16(ahf, bh1, acc1, 0, 0, 0);\
        acc1 = __builtin_amdgcn_mfma_f32_32x32x16_bf16(ahf, bl1, acc1, 0, 0, 0);\
        acc1 = __builtin_amdgcn_mfma_f32_32x32x16_bf16(alf, bh1, acc1, 0, 0, 0);\
      }                                                                         \
    }

  STAGE(0, 0);
  __syncthreads();
  #pragma unroll 1
  for (int s = 0; s < 32; ++s) {
    if (s + 1 < 32) STAGE((s + 1) & 1, s + 1);
    COMPUTE(s & 1);
    __syncthreads();
  }

  float* hq = y ? h1 : h0;
  #pragma unroll
  for (int reg = 0; reg < 16; ++reg) {
    const int row = (reg & 3) + 8 * (reg >> 2) + 4 * ks;       // 0..31
    const int gr = m0 + wr * 32 + row;
    const int gc0 = wc * 64 + fr;
    const int gc1 = wc * 64 + 32 + fr;
    float v0 = acc0[reg], v1 = acc1[reg];
    if (y == 0) { v0 += bias[gc0]; v1 += bias[gc1]; }
    hq[(size_t)gr * DSP + gc0] = v0;
    hq[(size_t)gr * DSP + gc1] = v1;
  }
  #undef STAGE
  #undef COMPUTE
}

// ---------------- K2: logits + softmax + importance-weighted accumulate --------
__global__ __launch_bounds__(256) void k2_logits(const float* __restrict__ h0,
                                                 const float* __restrict__ h1,
                                                 const float* __restrict__ embn,
                                                 const float* __restrict__ imp,
                                                 float* __restrict__ dense) {
  __shared__ __align__(16) float hs[128][36];
  __shared__ __align__(16) float es[16][516];
  __shared__ float ldsDense[512];
  const int tid = threadIdx.x;
  const int m0 = blockIdx.x * 32;
  const int seg = blockIdx.y;
  const int b = m0 >> 12;
  const int tr = tid >> 6;
  const int tc = tid & 63;

  ldsDense[tid] = 0.0f;
  ldsDense[tid + 256] = 0.0f;

  for (int i = tid; i < 32 * 128; i += 256) {
    const int r = i >> 7, k = i & 127;
    const size_t idx = (size_t)(m0 + r) * DSP + k;
    hs[k][r] = h0[idx] + h1[idx];
  }

  float acc[8][8] = {};
  const float* embSeg = embn + (size_t)seg * NSEG * DSP;

  for (int kt = 0; kt < 128; kt += 16) {
    __syncthreads();
    for (int i = tid; i < NSEG * 16; i += 256) {
      const int n = i >> 4, kk = i & 15;
      es[kk][n] = embSeg[(size_t)n * DSP + kt + kk];
    }
    __syncthreads();
    #pragma unroll
    for (int kk = 0; kk < 16; ++kk) {
      const int k = kt + kk;
      const float4 ha = *(const float4*)&hs[k][tr * 8];
      const float4 hb = *(const float4*)&hs[k][tr * 8 + 4];
      const float4 ea = *(const float4*)&es[kk][tc * 8];
      const float4 eb = *(const float4*)&es[kk][tc * 8 + 4];
      const float hv[8] = {ha.x, ha.y, ha.z, ha.w, hb.x, hb.y, hb.z, hb.w};
      const float ev[8] = {ea.x, ea.y, ea.z, ea.w, eb.x, eb.y, eb.z, eb.w};
      #pragma unroll
      for (int i = 0; i < 8; ++i)
        #pragma unroll
        for (int j = 0; j < 8; ++j)
          acc[i][j] = fmaf(hv[i], ev[j], acc[i][j]);
    }
  }

  float w[8];
  #pragma unroll
  for (int i = 0; i < 8; ++i) {
    float mx = acc[i][0];
    #pragma unroll
    for (int j = 1; j < 8; ++j) mx = fmaxf(mx, acc[i][j]);
    #pragma unroll
    for (int m = 1; m < 64; m <<= 1) mx = fmaxf(mx, __shfl_xor(mx, m));
    float s = 0.0f;
    #pragma unroll
    for (int j = 0; j < 8; ++j) {
      acc[i][j] = __expf(acc[i][j] - mx);
      s += acc[i][j];
    }
    #pragma unroll
    for (int m = 1; m < 64; m <<= 1) s += __shfl_xor(s, m);
    w[i] = imp[m0 + tr * 8 + i] / s;
  }

  #pragma unroll
  for (int j = 0; j < 8; ++j) {
    float p = 0.0f;
    #pragma unroll
    for (int i = 0; i < 8; ++i) p = fmaf(acc[i][j], w[i], p);
    atomicAdd(&ldsDense[tc * 8 + j], p);
  }
  __syncthreads();
  atomicAdd(&dense[b * 1536 + seg * NSEG + tid], ldsDense[tid]);
  atomicAdd(&dense[b * 1536 + seg * NSEG + tid + 256], ldsDense[tid + 256]);
}

// ---------------- K3: top-k sparsify + normalize + write outputs ---------------
__global__ __launch_bounds__(256) void k3_topk(const float* __restrict__ dense,
                                               float* __restrict__ out) {
  const int b = blockIdx.x;
  const int seg = blockIdx.y;
  const int tid = threadIdx.x;
  const int K = (seg == 0) ? 8 : ((seg == 1) ? 4 : 6);

  __shared__ float v[512];
  __shared__ float wv[8];
  __shared__ int wi[8];
  __shared__ float redv[4];
  __shared__ int redi[4];

  const float* src = dense + b * 1536 + seg * NSEG;
  v[tid] = src[tid];
  v[tid + 256] = src[tid + 256];
  __syncthreads();

  for (int t = 0; t < K; ++t) {
    const float v0 = v[tid], v1 = v[tid + 256];
    float bv; int bi;
    if (v1 > v0) { bv = v1; bi = tid + 256; } else { bv = v0; bi = tid; }
    #pragma unroll
    for (int m = 1; m < 64; m <<= 1) {
      const float ov = __shfl_xor(bv, m);
      const int oi = __shfl_xor(bi, m);
      if (ov > bv || (ov == bv && oi < bi)) { bv = ov; bi = oi; }
    }
    if ((tid & 63) == 0) { redv[tid >> 6] = bv; redi[tid >> 6] = bi; }
    __syncthreads();
    if (tid == 0) {
      float best = redv[0]; int besti = redi[0];
      for (int q = 1; q < 4; ++q)
        if (redv[q] > best || (redv[q] == best && redi[q] < besti)) {
          best = redv[q]; besti = redi[q];
        }
      wv[t] = best; wi[t] = besti;
      v[besti] = -3.0e38f;
    }
    __syncthreads();
  }

  float s = 1e-8f;
  for (int t = 0; t < K; ++t) s += wv[t];

  const int slot0 = (seg == 0) ? 0 : ((seg == 1) ? 1 : 3);
  float* o0 = out + slot0 * (BATCH * NSEG) + b * NSEG;
  o0[tid] = 0.0f; o0[tid + 256] = 0.0f;
  float* o1 = nullptr;
  if (seg == 1) {
    o1 = out + 2 * (BATCH * NSEG) + b * NSEG;
    o1[tid] = 0.0f; o1[tid + 256] = 0.0f;
  }
  __syncthreads();
  if (tid < K) {
    const float val = wv[tid] / s;
    o0[wi[tid]] = val;
    if (seg == 1) o1[wi[tid]] = val;
  }
}

// -------------------------------- launch ---------------------------------------
extern "C" void kernel_launch(void* const* d_in, const int* in_sizes, int n_in,
                              void* d_out, int out_size, void* d_ws, size_t ws_size,
                              hipStream_t stream) {
  (void)in_sizes; (void)n_in; (void)out_size; (void)ws_size;
  const float* x    = (const float*)d_in[0];
  const float* imp  = (const float*)d_in[1];
  const float* W    = (const float*)d_in[2];
  const float* bias = (const float*)d_in[3];
  const float* emb  = (const float*)d_in[4];
  float* out = (float*)d_out;

  // workspace carve (floats): embn | h0 | h1 | dense
  float* embn  = (float*)d_ws;                 // 1536*128
  float* h0    = embn + 196608;                // 16384*128
  float* h1    = h0 + 2097152;                 // 16384*128
  float* dense = h1 + 2097152;                 // 4*1536

  hipMemsetAsync(dense, 0, 6144 * sizeof(float), stream);

  k0_norm<<<1536, 64, 0, stream>>>(emb, embn);
  k1_mfma<<<dim3(ROWS / 128, 2), 512, 0, stream>>>(x, W, bias, h0, h1);
  k2_logits<<<dim3(ROWS / 32, 3), 256, 0, stream>>>(h0, h1, embn, imp, dense);
  k3_topk<<<dim3(BATCH, 3), 256, 0, stream>>>(dense, out);
}

// Round 3
// 114.174 us; speedup vs baseline: 4.7873x; 1.7061x over previous
//
#include <hip/hip_runtime.h>
#include <hip/hip_bf16.h>

// Problem constants
#define BATCH 4
#define S_TOT 4096
#define ROWS (BATCH * S_TOT)   // 16384
#define DM 2048
#define DSP 128
#define NSEG 512               // neurons per segment; 3 segments

typedef short short8 __attribute__((ext_vector_type(8)));
typedef float f32x16 __attribute__((ext_vector_type(16)));

// float -> bf16(RNE) bits; also returns the fp32 value of the bf16 for residual
static __device__ inline short f2bf(float v, float& back) {
  unsigned u = __float_as_uint(v);
  unsigned r = u + 0x7FFFu + ((u >> 16) & 1u);
  unsigned short hs = (unsigned short)(r >> 16);
  back = __uint_as_float(((unsigned)hs) << 16);
  return (short)hs;
}

// Fragment layout for a [R][128] matrix, per split:
//   idx = rowblk*4096 + kchunk*512 + lane*8 + elem,
//   rowblk=row>>5, kchunk=k>>4, lane=(row&31)+32*((k>>3)&1), elem=k&7.
// A wave's 16x32-k MFMA fragment load = 64 lanes x contiguous 16B.

// ---------------- K0: normalize neuron emb + pack frag layout ------------------
__global__ __launch_bounds__(64) void k0_norm(const float* __restrict__ emb,
                                              short* __restrict__ eHi,
                                              short* __restrict__ eLo) {
  const int row = blockIdx.x;          // 0..1535
  const int l = threadIdx.x;           // 0..63
  __shared__ short sh[128], sl[128];
  float2 v = *(const float2*)&emb[row * 128 + l * 2];
  float ss = v.x * v.x + v.y * v.y;
  #pragma unroll
  for (int m = 32; m; m >>= 1) ss += __shfl_xor(ss, m);
  const float inv = 1.0f / fmaxf(sqrtf(ss), 1e-12f);
  float bk;
  const float ox = v.x * inv, oy = v.y * inv;
  sh[2 * l] = f2bf(ox, bk);     sl[2 * l] = f2bf(ox - bk, bk);
  sh[2 * l + 1] = f2bf(oy, bk); sl[2 * l + 1] = f2bf(oy - bk, bk);
  __syncthreads();
  if (l < 32) {
    const int split = l >> 4, kc = (l >> 1) & 7, kh = l & 1;
    const short* src = (split ? sl : sh) + kc * 16 + kh * 8;
    const short8 val = *(const short8*)src;
    const size_t idx = (size_t)(row >> 5) * 4096 + kc * 512 +
                       ((row & 31) + 32 * kh) * 8;
    *(short8*)((split ? eLo : eHi) + idx) = val;
  }
}

// ---------------- K1: h = x @ W^T + b via bf16x3-split MFMA (unchanged) --------
__global__ __launch_bounds__(512, 2) void k1_mfma(const float* __restrict__ x,
                                                  const float* __restrict__ W,
                                                  const float* __restrict__ bias,
                                                  float* __restrict__ h0,
                                                  float* __restrict__ h1) {
  __shared__ __align__(16) short lds[2][4][4][128][8];   // 64 KB

  const int t = threadIdx.x;
  const int m0 = blockIdx.x * 128;
  const int y = blockIdx.y;              // K-half
  const int kb0 = y * 1024;

  const int sr = t >> 2;
  const int skg = t & 3;
  const float* xp = x + (size_t)(m0 + sr) * DM + kb0 + skg * 8;
  const float* wp = W + (size_t)sr * DM + kb0 + skg * 8;

  const int wave = t >> 6;
  const int lane = t & 63;
  const int wr = wave >> 1;
  const int wc = wave & 1;
  const int fr = lane & 31;
  const int ks = lane >> 5;

  f32x16 acc0 = {}; f32x16 acc1 = {};

  #define STAGE(buf, step)                                                      \
    {                                                                           \
      const int off = (step) * 32;                                              \
      float4 a0 = *(const float4*)(xp + off);                                   \
      float4 a1 = *(const float4*)(xp + off + 4);                               \
      float4 b0 = *(const float4*)(wp + off);                                   \
      float4 b1 = *(const float4*)(wp + off + 4);                               \
      short8 ah, al, bh, bl; float bk;                                          \
      const float av[8] = {a0.x,a0.y,a0.z,a0.w,a1.x,a1.y,a1.z,a1.w};            \
      const float bv[8] = {b0.x,b0.y,b0.z,b0.w,b1.x,b1.y,b1.z,b1.w};            \
      _Pragma("unroll")                                                         \
      for (int e = 0; e < 8; ++e) {                                             \
        ah[e] = f2bf(av[e], bk); al[e] = f2bf(av[e] - bk, bk);                  \
      }                                                                         \
      _Pragma("unroll")                                                         \
      for (int e = 0; e < 8; ++e) {                                             \
        bh[e] = f2bf(bv[e], bk); bl[e] = f2bf(bv[e] - bk, bk);                  \
      }                                                                         \
      *(short8*)&lds[buf][0][skg][sr][0] = ah;                                  \
      *(short8*)&lds[buf][1][skg][sr][0] = al;                                  \
      *(short8*)&lds[buf][2][skg][sr][0] = bh;                                  \
      *(short8*)&lds[buf][3][skg][sr][0] = bl;                                  \
    }

  #define COMPUTE(buf)                                                          \
    {                                                                           \
      _Pragma("unroll")                                                         \
      for (int kh = 0; kh < 2; ++kh) {                                          \
        const int kg = kh * 2 + ks;                                             \
        short8 ahf = *(const short8*)&lds[buf][0][kg][wr * 32 + fr][0];         \
        short8 alf = *(const short8*)&lds[buf][1][kg][wr * 32 + fr][0];         \
        short8 bh0 = *(const short8*)&lds[buf][2][kg][wc * 64 + fr][0];         \
        short8 bl0 = *(const short8*)&lds[buf][3][kg][wc * 64 + fr][0];         \
        short8 bh1 = *(const short8*)&lds[buf][2][kg][wc * 64 + 32 + fr][0];    \
        short8 bl1 = *(const short8*)&lds[buf][3][kg][wc * 64 + 32 + fr][0];    \
        acc0 = __builtin_amdgcn_mfma_f32_32x32x16_bf16(ahf, bh0, acc0, 0, 0, 0);\
        acc0 = __builtin_amdgcn_mfma_f32_32x32x16_bf16(ahf, bl0, acc0, 0, 0, 0);\
        acc0 = __builtin_amdgcn_mfma_f32_32x32x16_bf16(alf, bh0, acc0, 0, 0, 0);\
        acc1 = __builtin_amdgcn_mfma_f32_32x32x16_bf16(ahf, bh1, acc1, 0, 0, 0);\
        acc1 = __builtin_amdgcn_mfma_f32_32x32x16_bf16(ahf, bl1, acc1, 0, 0, 0);\
        acc1 = __builtin_amdgcn_mfma_f32_32x32x16_bf16(alf, bh1, acc1, 0, 0, 0);\
      }                                                                         \
    }

  STAGE(0, 0);
  __syncthreads();
  #pragma unroll 1
  for (int s = 0; s < 32; ++s) {
    if (s + 1 < 32) STAGE((s + 1) & 1, s + 1);
    COMPUTE(s & 1);
    __syncthreads();
  }

  float* hq = y ? h1 : h0;
  #pragma unroll
  for (int reg = 0; reg < 16; ++reg) {
    const int row = (reg & 3) + 8 * (reg >> 2) + 4 * ks;
    const int gr = m0 + wr * 32 + row;
    const int gc0 = wc * 64 + fr;
    const int gc1 = wc * 64 + 32 + fr;
    float v0 = acc0[reg], v1 = acc1[reg];
    if (y == 0) { v0 += bias[gc0]; v1 += bias[gc1]; }
    hq[(size_t)gr * DSP + gc0] = v0;
    hq[(size_t)gr * DSP + gc1] = v1;
  }
  #undef STAGE
  #undef COMPUTE
}

// ---------------- K1b: h = h0 + h1, split to bf16 hi/lo, pack frag layout ------
__global__ __launch_bounds__(256) void k1b_pack(const float* __restrict__ h0,
                                                const float* __restrict__ h1,
                                                short* __restrict__ hHi,
                                                short* __restrict__ hLo) {
  const int t = threadIdx.x;
  const int row = blockIdx.x * 16 + (t >> 4);
  const int c = t & 15;                 // 8-k chunk
  const float4* p0 = (const float4*)(h0 + (size_t)row * 128 + c * 8);
  const float4* p1 = (const float4*)(h1 + (size_t)row * 128 + c * 8);
  const float4 a0 = p0[0], a1 = p0[1], b0 = p1[0], b1 = p1[1];
  const float v[8] = {a0.x + b0.x, a0.y + b0.y, a0.z + b0.z, a0.w + b0.w,
                      a1.x + b1.x, a1.y + b1.y, a1.z + b1.z, a1.w + b1.w};
  short8 hiv, lov; float bk;
  #pragma unroll
  for (int e = 0; e < 8; ++e) {
    hiv[e] = f2bf(v[e], bk); lov[e] = f2bf(v[e] - bk, bk);
  }
  const int kc = c >> 1, kh = c & 1;
  const size_t idx = (size_t)(row >> 5) * 4096 + kc * 512 +
                     ((row & 31) + 32 * kh) * 8;
  *(short8*)(hHi + idx) = hiv;
  *(short8*)(hLo + idx) = lov;
}

// ---------------- K2: logits via MFMA + softmax + weighted col-sum -------------
// grid (256 row-tiles of 64, 3 segments), 512 threads = 8 waves.
// wave: wr=wave>>2 (row half), wc=wave&3 (128-neuron group, 4 tiles of 32).
__global__ __launch_bounds__(512, 2) void k2_mfma(const short* __restrict__ hHi,
                                                  const short* __restrict__ hLo,
                                                  const short* __restrict__ eHi,
                                                  const short* __restrict__ eLo,
                                                  const float* __restrict__ imp,
                                                  float* __restrict__ partials) {
  const int t = threadIdx.x;
  const int m0 = blockIdx.x * 64;
  const int seg = blockIdx.y;
  const int wave = t >> 6, lane = t & 63;
  const int wr = wave >> 2;
  const int wc = wave & 3;
  const int fr = lane & 31;
  const int hi = lane >> 5;

  __shared__ float redA[2][32][4];
  __shared__ float redB[2][32][4];
  __shared__ float ldsD[2][512];

  f32x16 acc[4] = {};

  const short8* pAh = (const short8*)hHi + ((m0 >> 5) + wr) * 512 + lane;
  const short8* pAl = (const short8*)hLo + ((m0 >> 5) + wr) * 512 + lane;
  const short8* pBh = (const short8*)eHi + (seg * 16 + wc * 4) * 512 + lane;
  const short8* pBl = (const short8*)eLo + (seg * 16 + wc * 4) * 512 + lane;

  #pragma unroll
  for (int kc = 0; kc < 8; ++kc) {
    const short8 ah = pAh[kc * 64];
    const short8 al = pAl[kc * 64];
    #pragma unroll
    for (int t2 = 0; t2 < 4; ++t2) {
      const short8 bh = pBh[t2 * 512 + kc * 64];
      const short8 bl = pBl[t2 * 512 + kc * 64];
      acc[t2] = __builtin_amdgcn_mfma_f32_32x32x16_bf16(ah, bh, acc[t2], 0, 0, 0);
      acc[t2] = __builtin_amdgcn_mfma_f32_32x32x16_bf16(ah, bl, acc[t2], 0, 0, 0);
      acc[t2] = __builtin_amdgcn_mfma_f32_32x32x16_bf16(al, bh, acc[t2], 0, 0, 0);
    }
  }

  // ---- row max (over 512 neurons) ----
  float mx[16];
  #pragma unroll
  for (int r = 0; r < 16; ++r) {
    float m = fmaxf(fmaxf(acc[0][r], acc[1][r]), fmaxf(acc[2][r], acc[3][r]));
    #pragma unroll
    for (int k = 1; k < 32; k <<= 1) m = fmaxf(m, __shfl_xor(m, k));
    mx[r] = m;
  }
  if (fr == 0) {
    #pragma unroll
    for (int r = 0; r < 16; ++r)
      redA[wr][(r & 3) + 8 * (r >> 2) + 4 * hi][wc] = mx[r];
  }
  __syncthreads();
  float M[16];
  #pragma unroll
  for (int r = 0; r < 16; ++r) {
    const int row = (r & 3) + 8 * (r >> 2) + 4 * hi;
    M[r] = fmaxf(fmaxf(redA[wr][row][0], redA[wr][row][1]),
                 fmaxf(redA[wr][row][2], redA[wr][row][3]));
  }

  // ---- exp + row sum ----
  float sm[16];
  #pragma unroll
  for (int r = 0; r < 16; ++r) {
    float s = 0.0f;
    #pragma unroll
    for (int t2 = 0; t2 < 4; ++t2) {
      const float p = __expf(acc[t2][r] - M[r]);
      acc[t2][r] = p;
      s += p;
    }
    #pragma unroll
    for (int k = 1; k < 32; k <<= 1) s += __shfl_xor(s, k);
    sm[r] = s;
  }
  if (fr == 0) {
    #pragma unroll
    for (int r = 0; r < 16; ++r)
      redB[wr][(r & 3) + 8 * (r >> 2) + 4 * hi][wc] = sm[r];
  }
  __syncthreads();
  float w[16];
  #pragma unroll
  for (int r = 0; r < 16; ++r) {
    const int row = (r & 3) + 8 * (r >> 2) + 4 * hi;
    const float S = (redB[wr][row][0] + redB[wr][row][1]) +
                    (redB[wr][row][2] + redB[wr][row][3]);
    w[r] = imp[m0 + wr * 32 + row] / S;
  }

  // ---- importance-weighted column partials (deterministic) ----
  #pragma unroll
  for (int t2 = 0; t2 < 4; ++t2) {
    float d = 0.0f;
    #pragma unroll
    for (int r = 0; r < 16; ++r) d = fmaf(acc[t2][r], w[r], d);
    d += __shfl_xor(d, 32);
    if (hi == 0) ldsD[wr][wc * 128 + t2 * 32 + fr] = d;
  }
  __syncthreads();
  partials[((size_t)seg * 256 + blockIdx.x) * 512 + t] = ldsD[0][t] + ldsD[1][t];
}

// ---------------- K3: sum partials (fixed order) + top-k + write ---------------
__global__ __launch_bounds__(256) void k3_topk(const float* __restrict__ partials,
                                               float* __restrict__ out) {
  const int b = blockIdx.x;
  const int seg = blockIdx.y;
  const int tid = threadIdx.x;
  const int K = (seg == 0) ? 8 : ((seg == 1) ? 4 : 6);

  __shared__ float v[512];
  __shared__ float wv[8];
  __shared__ int wi[8];
  __shared__ float redv[4];
  __shared__ int redi[4];

  const float* src = partials + ((size_t)seg * 256 + b * 64) * 512;
  float a0 = 0.0f, a1 = 0.0f;
  for (int j = 0; j < 64; ++j) {
    a0 += src[(size_t)j * 512 + tid];
    a1 += src[(size_t)j * 512 + tid + 256];
  }
  v[tid] = a0;
  v[tid + 256] = a1;
  __syncthreads();

  for (int t = 0; t < K; ++t) {
    const float v0 = v[tid], v1 = v[tid + 256];
    float bv; int bi;
    if (v1 > v0) { bv = v1; bi = tid + 256; } else { bv = v0; bi = tid; }
    #pragma unroll
    for (int m = 1; m < 64; m <<= 1) {
      const float ov = __shfl_xor(bv, m);
      const int oi = __shfl_xor(bi, m);
      if (ov > bv || (ov == bv && oi < bi)) { bv = ov; bi = oi; }
    }
    if ((tid & 63) == 0) { redv[tid >> 6] = bv; redi[tid >> 6] = bi; }
    __syncthreads();
    if (tid == 0) {
      float best = redv[0]; int besti = redi[0];
      for (int q = 1; q < 4; ++q)
        if (redv[q] > best || (redv[q] == best && redi[q] < besti)) {
          best = redv[q]; besti = redi[q];
        }
      wv[t] = best; wi[t] = besti;
      v[besti] = -3.0e38f;
    }
    __syncthreads();
  }

  float s = 1e-8f;
  for (int t = 0; t < K; ++t) s += wv[t];

  const int slot0 = (seg == 0) ? 0 : ((seg == 1) ? 1 : 3);
  float* o0 = out + slot0 * (BATCH * NSEG) + b * NSEG;
  o0[tid] = 0.0f; o0[tid + 256] = 0.0f;
  float* o1 = nullptr;
  if (seg == 1) {
    o1 = out + 2 * (BATCH * NSEG) + b * NSEG;
    o1[tid] = 0.0f; o1[tid + 256] = 0.0f;
  }
  __syncthreads();
  if (tid < K) {
    const float val = wv[tid] / s;
    o0[wi[tid]] = val;
    if (seg == 1) o1[wi[tid]] = val;
  }
}

// -------------------------------- launch ---------------------------------------
extern "C" void kernel_launch(void* const* d_in, const int* in_sizes, int n_in,
                              void* d_out, int out_size, void* d_ws, size_t ws_size,
                              hipStream_t stream) {
  (void)in_sizes; (void)n_in; (void)out_size; (void)ws_size;
  const float* x    = (const float*)d_in[0];
  const float* imp  = (const float*)d_in[1];
  const float* W    = (const float*)d_in[2];
  const float* bias = (const float*)d_in[3];
  const float* emb  = (const float*)d_in[4];
  float* out = (float*)d_out;

  // workspace carve: h0 | h1 | partials (f32), then hHi | hLo | eHi | eLo (i16)
  float* h0       = (float*)d_ws;              // 2097152 f32
  float* h1       = h0 + 2097152;              // 2097152 f32
  float* partials = h1 + 2097152;              // 768*512 f32
  short* hHi      = (short*)(partials + 768 * 512);   // 2097152 i16
  short* hLo      = hHi + 2097152;
  short* eHi      = hLo + 2097152;             // 196608 i16
  short* eLo      = eHi + 196608;

  k0_norm<<<1536, 64, 0, stream>>>(emb, eHi, eLo);
  k1_mfma<<<dim3(ROWS / 128, 2), 512, 0, stream>>>(x, W, bias, h0, h1);
  k1b_pack<<<ROWS / 16, 256, 0, stream>>>(h0, h1, hHi, hLo);
  k2_mfma<<<dim3(ROWS / 64, 3), 512, 0, stream>>>(hHi, hLo, eHi, eLo, imp, partials);
  k3_topk<<<dim3(BATCH, 3), 256, 0, stream>>>(partials, out);
}